// Round 11
// baseline (266.566 us; speedup 1.0000x reference)
//
#include <hip/hip_runtime.h>
#include <hip/hip_bf16.h>
#include <hip/hip_fp16.h>

#define NN 50000
#define INCH 512
#define OUTCH 64
#define NTILES 3125       // 50000 / 16 (exact)
#define MAXD 48           // ELL slots per row
#define GB 782            // gemm blocks: ceil(3125 tiles / 4 waves)
#define SCB 1024          // scatter blocks (128 per XCD partition)
#define RPB 32            // rows per bucket
#define NBUCKET 1563      // ceil(50000 / 32)
#define NPART 8           // sub-buckets per bucket (one per XCD under round-robin)
#define BCAPP 112         // records per sub-bucket: Poisson(64) + 6 sigma
#define TSTR 16           // btail counter stride (64 B): no same-line atomic pileup

typedef __attribute__((ext_vector_type(8))) short short8;
typedef __attribute__((ext_vector_type(4))) float floatx4;
typedef unsigned long long u64;

__device__ __forceinline__ unsigned packbf2(float a, float b) {
    __hip_bfloat162 h = __float22bfloat162_rn(make_float2(a, b));  // v_cvt_pk_bf16_f32 RNE
    unsigned r;
    __builtin_memcpy(&r, &h, 4);
    return r;
}
__device__ __forceinline__ unsigned short f2bf(float f) {
    unsigned u = __float_as_uint(f);
    return (unsigned short)((u + 0x7FFFu + ((u >> 16) & 1u)) >> 16);  // RNE
}
__device__ __forceinline__ float bf2f(unsigned short u) {
    return __uint_as_float(((unsigned)u) << 16);
}

// ------------- prep: zero padded sub-bucket tails + convert W -> bf16 [n][k] ----------
__global__ __launch_bounds__(256) void prep_kernel(const float* __restrict__ W,
                                                   unsigned short* __restrict__ Wbf,
                                                   int* __restrict__ btail) {
    const int i = blockIdx.x * 256 + threadIdx.x;
    if (i < (NBUCKET * NPART * TSTR) / 4)   // 200064 ints = 50016 uint4
        *reinterpret_cast<uint4*>(btail + i * 4) = uint4{0u, 0u, 0u, 0u};
    if (i < INCH * OUTCH) {
        const int k = i >> 6;          // W is [k][n], read coalesced
        const int n = i & 63;
        Wbf[n * INCH + k] = f2bf(W[i]);
    }
}

// ---------------- pure GEMM: feat[N,512] @ W -> x0 bf16 [N,64] ----------
// De-fused from the scatter (no churn interference). feat loads are CACHED
// (not nt): feat is re-read every iteration and fits the 256 MB L3 — nt's
// evict-first hint was forcing a ~50 MB HBM refetch each iteration.
// x0 stores cached too: hop-1's random gathers re-read them from L3.
__global__ __launch_bounds__(256, 4) void gemm_kernel(
        const float* __restrict__ A, const unsigned short* __restrict__ Wbf,
        unsigned short* __restrict__ C) {
    __shared__ unsigned short ldsT[4][16 * 64];   // 2 KB per wave
    const int t = threadIdx.x;
    const int lane = t & 63;
    const int wave = t >> 6;
    const int tile = blockIdx.x * 4 + wave;
    if (tile >= NTILES) return;
    const int rbase = tile * 16;
    const int frow = lane & 15;
    const int quad = lane >> 4;
    const float* Ap = A + (size_t)(rbase + frow) * INCH + quad * 8;
    const unsigned short* Bp = Wbf + frow * INCH + quad * 8;

    floatx4 acc[4] = {floatx4{0,0,0,0}, floatx4{0,0,0,0}, floatx4{0,0,0,0}, floatx4{0,0,0,0}};

#pragma unroll
    for (int c = 0; c < 16; ++c) {
        const float4 a0 = *(const float4*)(Ap + c * 32);
        const float4 a1 = *(const float4*)(Ap + c * 32 + 4);
        short8 bfr[4];
#pragma unroll
        for (int f = 0; f < 4; ++f)   // Wbf hot: normal cached loads
            bfr[f] = *(const short8*)(Bp + (size_t)f * 16 * INCH + c * 32);
        uint4 au;
        au.x = packbf2(a0.x, a0.y);
        au.y = packbf2(a0.z, a0.w);
        au.z = packbf2(a1.x, a1.y);
        au.w = packbf2(a1.z, a1.w);
        const short8 af = *(const short8*)&au;
#pragma unroll
        for (int f = 0; f < 4; ++f)
            acc[f] = __builtin_amdgcn_mfma_f32_16x16x32_bf16(af, bfr[f], acc[f], 0, 0, 0);
    }

    // C/D layout: col = f*16 + frow, row = quad*4 + reg   [m89]
    unsigned short* myT = ldsT[wave];
#pragma unroll
    for (int f = 0; f < 4; ++f)
#pragma unroll
        for (int reg = 0; reg < 4; ++reg)
            myT[(quad * 4 + reg) * 64 + f * 16 + frow] = f2bf(acc[f][reg]);
    // wave-local: ds ordering handled by lgkmcnt, no barrier needed
    unsigned short* Cw = C + (size_t)rbase * OUTCH;
#pragma unroll
    for (int it = 0; it < 2; ++it) {
        const short8 v = *(const short8*)&myT[it * 512 + lane * 8];
        *(short8*)(Cw + it * 512 + lane * 8) = v;
    }
}

// ---------------- scatter: partitioned dense bucket append (standalone) ----------
// Sub-bucket per blockIdx&7 -> all writers of a bucket front-line share one
// XCD under round-robin dispatch; tail counters padded to 64 B (<=64 atomics
// each). Edge-list loads nt (single-use stream).
__global__ __launch_bounds__(256) void scatter_kernel(
        const int* __restrict__ rows, const int* __restrict__ cols,
        const float* __restrict__ vals, int* __restrict__ btail,
        u64* __restrict__ buckets, int E_) {
    const int part = blockIdx.x & 7;              // XCD-aligned under round-robin
    for (int e = blockIdx.x * 256 + threadIdx.x; e < E_; e += SCB * 256) {
        const int r = __builtin_nontemporal_load(rows + e);
        const int c = __builtin_nontemporal_load(cols + e);
        const float v = __builtin_nontemporal_load(vals + e);
        const unsigned short hv = __half_as_ushort(__float2half(v));
        const u64 rec = (u64)(unsigned)(r & 0xFFFF)
                      | ((u64)(unsigned)(c & 0xFFFF) << 16)
                      | ((u64)hv << 32);
        const int sb = (r >> 5) * NPART + part;
        const int pos = atomicAdd(&btail[sb * TSTR], 1);
        if (pos < BCAPP)
            buckets[(size_t)sb * BCAPP + pos] = rec;
    }
}

// ---------------- bucketize: block per bucket, buckets -> ELL slice + deg ----------
// ONE LDS atomic per record (slot assignment), staged ELL slice written out
// fully coalesced. Replaces the random global ELL scatter.
__global__ __launch_bounds__(256) void bucketize(
        const int* __restrict__ btail, const u64* __restrict__ buckets,
        unsigned* __restrict__ ell, int* __restrict__ deg) {
    __shared__ int cnt[RPB];
    __shared__ __align__(16) unsigned stage[RPB * MAXD];   // 6 KB
    const int t = threadIdx.x;
    const int b = blockIdx.x;                  // grid = NBUCKET

    if (t < RPB) cnt[t] = 0;
    for (int j = t; j < RPB * MAXD; j += 256) stage[j] = 0u;
    __syncthreads();

    for (int part = 0; part < NPART; ++part) {
        const int sb = b * NPART + part;
        int n = btail[sb * TSTR];
        n = n < BCAPP ? n : BCAPP;
        const u64* base = buckets + (size_t)sb * BCAPP;
        for (int i = t; i < n; i += 256) {
            const u64 rec = __builtin_nontemporal_load(base + i);
            const int rloc = (int)rec & 31;    // row & 31 == row - 32*b
            const int slot = atomicAdd(&cnt[rloc], 1);
            if (slot < MAXD)
                stage[rloc * MAXD + slot] = (unsigned)(rec >> 16);  // col | hv<<16
        }
    }
    __syncthreads();

    // coalesced write-out: 6 KB ELL slice (rows 32b..32b+31 contiguous)
    uint4* dst = (uint4*)(ell + (size_t)b * RPB * MAXD);
    const uint4* src = (const uint4*)stage;
    for (int j = t; j < (RPB * MAXD) / 4; j += 256) dst[j] = src[j];
    const int row = b * RPB + t;
    if (t < RPB && row < NN) {
        int d = cnt[t];
        deg[row] = d < MAXD ? d : MAXD;
    }
}

// ---------------- SpMM over ELL: wave per row, 8 edge-slots x 8 ch-lanes ----------
// The proven ~56us/hop kernel, at the empirical ~2.1 TB/s random-line ceiling.
template <bool LAST>
__global__ __launch_bounds__(256) void spmm_full(const int* __restrict__ deg,
                                                 const unsigned* __restrict__ ell,
                                                 const unsigned short* __restrict__ xin,
                                                 void* __restrict__ xout_,
                                                 const float* __restrict__ bias) {
    const int t = threadIdx.x;
    const int lane = t & 63;
    const int eslot = lane >> 3;              // 0..7: edge slot group
    const int cg = lane & 7;                  // channel group: 8 ch (16B) each
    const int row = blockIdx.x * 4 + (t >> 6);   // grid = 12500, NN exact
    int d = deg[row];
    d = d < MAXD ? d : MAXD;
    const unsigned* eb = ell + (size_t)row * MAXD;

    unsigned p[6];
#pragma unroll
    for (int j = 0; j < 6; ++j)
        p[j] = __builtin_nontemporal_load(eb + eslot + 8 * j);
#pragma unroll
    for (int j = 0; j < 6; ++j)
        if (eslot + 8 * j >= d) p[j] = 0u;    // col 0, val 0 -> contributes 0

    const unsigned short* xh = xin + cg * 8;
    float acc[8] = {0.f, 0.f, 0.f, 0.f, 0.f, 0.f, 0.f, 0.f};

#pragma unroll
    for (int j = 0; j < 6; ++j) {
        if (d > 8 * j) {                      // wave-uniform round skip
            const unsigned P = p[j];
            const short8 xv = *(const short8*)(xh + (size_t)(P & 0xFFFFu) * OUTCH);
            const float v = __half2float(__ushort_as_half((unsigned short)(P >> 16)));
#pragma unroll
            for (int k = 0; k < 8; ++k)
                acc[k] = fmaf(v, bf2f((unsigned short)xv[k]), acc[k]);
        }
    }

#pragma unroll
    for (int k = 0; k < 8; ++k) {
        acc[k] += __shfl_xor(acc[k], 8, 64);
        acc[k] += __shfl_xor(acc[k], 16, 64);
        acc[k] += __shfl_xor(acc[k], 32, 64);
    }

    if (eslot == 0) {
        const int chb = cg * 8;
        if (LAST) {
            float* op = (float*)xout_ + (size_t)row * OUTCH + chb;
            const floatx4 b0 = *(const floatx4*)(bias + chb);
            const floatx4 b1 = *(const floatx4*)(bias + chb + 4);
            floatx4 o0, o1;
            o0[0] = acc[0] + b0[0]; o0[1] = acc[1] + b0[1];
            o0[2] = acc[2] + b0[2]; o0[3] = acc[3] + b0[3];
            o1[0] = acc[4] + b1[0]; o1[1] = acc[5] + b1[1];
            o1[2] = acc[6] + b1[2]; o1[3] = acc[7] + b1[3];
            __builtin_nontemporal_store(o0, (floatx4*)op);      // final out: true stream
            __builtin_nontemporal_store(o1, (floatx4*)(op + 4));
        } else {
            // x1 is re-read by hop-2 gathers: cached store keeps it L3-resident
            unsigned short* op = (unsigned short*)xout_ + (size_t)row * OUTCH + chb;
            short8 o;
#pragma unroll
            for (int k = 0; k < 8; ++k) o[k] = (short)f2bf(acc[k]);
            *(short8*)op = o;
        }
    }
}

extern "C" void kernel_launch(void* const* d_in, const int* in_sizes, int n_in,
                              void* d_out, int out_size, void* d_ws, size_t ws_size,
                              hipStream_t stream) {
    const int*   adj   = (const int*)d_in[0];     // [2, E]
    const float* avals = (const float*)d_in[1];   // [E]
    const float* feat  = (const float*)d_in[2];   // [N, 512]
    const float* W     = (const float*)d_in[3];   // [512, 64]
    const float* bias  = (const float*)d_in[4];   // [64]
    float* out = (float*)d_out;

    const int E_ = in_sizes[1];
    const int* rows = adj;
    const int* cols = adj + E_;

    // workspace layout (16B-aligned segments), total ~35 MB
    unsigned short* x0  = (unsigned short*)d_ws;             // N*64 bf16 (6.4 MB)
    unsigned short* x1  = x0 + (size_t)NN * OUTCH;           // N*64 bf16 (6.4 MB)
    unsigned short* Wbf = x1 + (size_t)NN * OUTCH;           // 64*512 bf16 (64 KB)
    unsigned* ell = (unsigned*)(Wbf + (size_t)OUTCH * INCH); // 1563*1536 u32 (9.6 MB)
    u64* buckets = (u64*)(ell + (size_t)NBUCKET * RPB * MAXD); // 1563*8*112 u64 (11.2 MB)
    int* btail = (int*)(buckets + (size_t)NBUCKET * NPART * BCAPP); // padded (800 KB)
    int* deg = btail + NBUCKET * NPART * TSTR;               // N int (200 KB)

    // ---- prep: zero padded tails + convert W to bf16 [n][k] ----
    prep_kernel<<<196, 256, 0, stream>>>(W, Wbf, btail);

    // ---- dense projection (bf16 MFMA), de-fused ----
    gemm_kernel<<<GB, 256, 0, stream>>>(feat, Wbf, x0);

    // ---- partitioned dense bucket append, de-fused ----
    scatter_kernel<<<SCB, 256, 0, stream>>>(rows, cols, avals, btail, buckets, E_);

    // ---- buckets -> ELL (coalesced) + deg ----
    bucketize<<<NBUCKET, 256, 0, stream>>>(btail, buckets, ell, deg);

    // ---- two SpMM hops; bias fused into the last ----
    spmm_full<false><<<NN / 4, 256, 0, stream>>>(deg, ell, x0, x1, nullptr);
    spmm_full<true><<<NN / 4, 256, 0, stream>>>(deg, ell, x1, out, bias);
}

// Round 12
// 250.559 us; speedup vs baseline: 1.0639x; 1.0639x over previous
//
#include <hip/hip_runtime.h>
#include <hip/hip_bf16.h>
#include <hip/hip_fp16.h>

#define NN 50000
#define INCH 512
#define OUTCH 64
#define NTILES 3125       // 50000 / 16 (exact)
#define MAXD 48           // ELL slots per row; P(Poisson(16) > 48) ~ 1e-11 per row
#define GB 782            // gemm blocks: ceil(3125 tiles / 4 waves)
#define SCB 128           // scatter blocks (1 per CU, big-LDS)
#define RPB 128           // rows per bucket
#define NB 391            // ceil(50000 / 128)
#define LCAP 40           // LDS records per (block,bucket) cell; overflow -> global spill
#define BCAP 2400         // records per global bucket: Poisson(2048) + 7.8 sigma
#define TSTR 16           // gtail counter stride (64 B)

typedef __attribute__((ext_vector_type(8))) short short8;
typedef __attribute__((ext_vector_type(4))) float floatx4;
typedef unsigned long long u64;

__device__ __forceinline__ unsigned packbf2(float a, float b) {
    __hip_bfloat162 h = __float22bfloat162_rn(make_float2(a, b));  // v_cvt_pk_bf16_f32 RNE
    unsigned r;
    __builtin_memcpy(&r, &h, 4);
    return r;
}
__device__ __forceinline__ unsigned short f2bf(float f) {
    unsigned u = __float_as_uint(f);
    return (unsigned short)((u + 0x7FFFu + ((u >> 16) & 1u)) >> 16);  // RNE
}
__device__ __forceinline__ float bf2f(unsigned short u) {
    return __uint_as_float(((unsigned)u) << 16);
}

// ------------- prep: zero padded bucket tails + convert W -> bf16 [n][k] ----------
__global__ __launch_bounds__(256) void prep_kernel(const float* __restrict__ W,
                                                   unsigned short* __restrict__ Wbf,
                                                   int* __restrict__ gtail) {
    const int i = blockIdx.x * 256 + threadIdx.x;
    if (i < (NB * TSTR + 3) / 4)
        *reinterpret_cast<uint4*>(gtail + i * 4) = uint4{0u, 0u, 0u, 0u};
    if (i < INCH * OUTCH) {
        const int k = i >> 6;          // W is [k][n], read coalesced
        const int n = i & 63;
        Wbf[n * INCH + k] = f2bf(W[i]);
    }
}

// ---------------- pure GEMM: feat[N,512] @ W -> x0 bf16 [N,64] ----------
__global__ __launch_bounds__(256, 4) void gemm_kernel(
        const float* __restrict__ A, const unsigned short* __restrict__ Wbf,
        unsigned short* __restrict__ C) {
    __shared__ unsigned short ldsT[4][16 * 64];   // 2 KB per wave
    const int t = threadIdx.x;
    const int lane = t & 63;
    const int wave = t >> 6;
    const int tile = blockIdx.x * 4 + wave;
    if (tile >= NTILES) return;
    const int rbase = tile * 16;
    const int frow = lane & 15;
    const int quad = lane >> 4;
    const float* Ap = A + (size_t)(rbase + frow) * INCH + quad * 8;
    const unsigned short* Bp = Wbf + frow * INCH + quad * 8;

    floatx4 acc[4] = {floatx4{0,0,0,0}, floatx4{0,0,0,0}, floatx4{0,0,0,0}, floatx4{0,0,0,0}};

#pragma unroll
    for (int c = 0; c < 16; ++c) {
        const float4 a0 = *(const float4*)(Ap + c * 32);
        const float4 a1 = *(const float4*)(Ap + c * 32 + 4);
        short8 bfr[4];
#pragma unroll
        for (int f = 0; f < 4; ++f)
            bfr[f] = *(const short8*)(Bp + (size_t)f * 16 * INCH + c * 32);
        uint4 au;
        au.x = packbf2(a0.x, a0.y);
        au.y = packbf2(a0.z, a0.w);
        au.z = packbf2(a1.x, a1.y);
        au.w = packbf2(a1.z, a1.w);
        const short8 af = *(const short8*)&au;
#pragma unroll
        for (int f = 0; f < 4; ++f)
            acc[f] = __builtin_amdgcn_mfma_f32_16x16x32_bf16(af, bfr[f], acc[f], 0, 0, 0);
    }

    // C/D layout: col = f*16 + frow, row = quad*4 + reg   [m89]
    unsigned short* myT = ldsT[wave];
#pragma unroll
    for (int f = 0; f < 4; ++f)
#pragma unroll
        for (int reg = 0; reg < 4; ++reg)
            myT[(quad * 4 + reg) * 64 + f * 16 + frow] = f2bf(acc[f][reg]);
    // wave-local: ds ordering handled by lgkmcnt, no barrier needed
    unsigned short* Cw = C + (size_t)rbase * OUTCH;
#pragma unroll
    for (int it = 0; it < 2; ++it) {
        const short8 v = *(const short8*)&myT[it * 512 + lane * 8];
        *(short8*)(Cw + it * 512 + lane * 8) = v;
    }
}

// ---------------- LDS-chunked scatter: 1 block/CU, per-bucket LDS cells -------------
// Each block stages records in [NB][LCAP] LDS cells and flushes each cell ONCE
// as a contiguous run via a single atomicAdd(tail, n) reservation -> ~50k dense
// flushes instead of 800k scattered 8B stores (the ~25 MB line churn + 45 us).
// Cell overflow (P ~1e-6) takes a direct global spill path: correctness-safe.
__global__ __launch_bounds__(256, 1) void scatter_chunked(
        const int* __restrict__ rows, const int* __restrict__ cols,
        const float* __restrict__ vals, int* __restrict__ gtail,
        u64* __restrict__ gbuckets, int E_) {
    extern __shared__ char ldsraw[];
    u64* lstage = (u64*)ldsraw;                      // [NB][LCAP]  125.1 KB
    int* lcnt = (int*)(lstage + (size_t)NB * LCAP);  // [NB]        1.6 KB
    const int t = threadIdx.x;

    for (int j = t; j < NB; j += 256) lcnt[j] = 0;
    __syncthreads();

    for (int e = blockIdx.x * 256 + t; e < E_; e += SCB * 256) {
        const int r = __builtin_nontemporal_load(rows + e);
        const int c = __builtin_nontemporal_load(cols + e);
        const float v = __builtin_nontemporal_load(vals + e);
        const unsigned short hv = __half_as_ushort(__float2half(v));
        const u64 rec = (u64)(unsigned)(r & 0xFFFF)
                      | ((u64)(unsigned)(c & 0xFFFF) << 16)
                      | ((u64)hv << 32);
        const int b = r >> 7;                        // bucket = row / 128
        const int pos = atomicAdd(&lcnt[b], 1);
        if (pos < LCAP) {
            lstage[(size_t)b * LCAP + pos] = rec;
        } else {                                     // rare spill: direct global
            const int gp = atomicAdd(&gtail[b * TSTR], 1);
            if (gp < BCAP) gbuckets[(size_t)b * BCAP + gp] = rec;
        }
    }
    __syncthreads();

    // one dense flush per non-empty cell
    for (int j = t; j < NB; j += 256) {
        int n = lcnt[j];
        n = n < LCAP ? n : LCAP;
        if (n > 0) {
            const int pos = atomicAdd(&gtail[j * TSTR], n);
            u64* dst = gbuckets + (size_t)j * BCAP;
            const u64* src = lstage + (size_t)j * LCAP;
            for (int k = 0; k < n; ++k)
                if (pos + k < BCAP) dst[pos + k] = src[k];
        }
    }
}

// ---------------- bucketize: block per 128-row bucket -> ELL slice + deg ----------
// ONE LDS atomic per record; ELL slice written fully coalesced (uint4).
__global__ __launch_bounds__(512) void bucketize(
        const int* __restrict__ gtail, const u64* __restrict__ gbuckets,
        unsigned* __restrict__ ell, int* __restrict__ deg) {
    __shared__ int cnt[RPB];
    __shared__ __align__(16) unsigned stage[RPB * MAXD];   // 24.5 KB
    const int t = threadIdx.x;
    const int b = blockIdx.x;                  // grid = NB

    if (t < RPB) cnt[t] = 0;
    for (int j = t; j < RPB * MAXD; j += 512) stage[j] = 0u;
    __syncthreads();

    int n = gtail[b * TSTR];
    n = n < BCAP ? n : BCAP;
    const u64* base = gbuckets + (size_t)b * BCAP;
    for (int i = t; i < n; i += 512) {
        const u64 rec = __builtin_nontemporal_load(base + i);
        const int rloc = (int)rec & 127;       // row & 127 (bucket = row>>7)
        const int slot = atomicAdd(&cnt[rloc], 1);
        if (slot < MAXD)
            stage[rloc * MAXD + slot] = (unsigned)(rec >> 16);  // col | hv<<16
    }
    __syncthreads();

    const int nrows = (NN - b * RPB) < RPB ? (NN - b * RPB) : RPB;  // last: 80
    uint4* dst = (uint4*)(ell + (size_t)b * RPB * MAXD);
    const uint4* src = (const uint4*)stage;
    for (int j = t; j < (nrows * MAXD) / 4; j += 512) dst[j] = src[j];
    if (t < nrows) {
        int d = cnt[t];
        deg[b * RPB + t] = d < MAXD ? d : MAXD;
    }
}

// ---------------- SpMM over ELL: wave per row, 8 edge-slots x 8 ch-lanes ----------
// The proven ~56us/hop kernel at the empirical random-line ceiling.
template <bool LAST>
__global__ __launch_bounds__(256) void spmm_full(const int* __restrict__ deg,
                                                 const unsigned* __restrict__ ell,
                                                 const unsigned short* __restrict__ xin,
                                                 void* __restrict__ xout_,
                                                 const float* __restrict__ bias) {
    const int t = threadIdx.x;
    const int lane = t & 63;
    const int eslot = lane >> 3;              // 0..7: edge slot group
    const int cg = lane & 7;                  // channel group: 8 ch (16B) each
    const int row = blockIdx.x * 4 + (t >> 6);   // grid = 12500, NN exact
    int d = deg[row];
    d = d < MAXD ? d : MAXD;
    const unsigned* eb = ell + (size_t)row * MAXD;

    unsigned p[6];
#pragma unroll
    for (int j = 0; j < 6; ++j)
        p[j] = __builtin_nontemporal_load(eb + eslot + 8 * j);
#pragma unroll
    for (int j = 0; j < 6; ++j)
        if (eslot + 8 * j >= d) p[j] = 0u;    // col 0, val 0 -> contributes 0

    const unsigned short* xh = xin + cg * 8;
    float acc[8] = {0.f, 0.f, 0.f, 0.f, 0.f, 0.f, 0.f, 0.f};

#pragma unroll
    for (int j = 0; j < 6; ++j) {
        if (d > 8 * j) {                      // wave-uniform round skip
            const unsigned P = p[j];
            const short8 xv = *(const short8*)(xh + (size_t)(P & 0xFFFFu) * OUTCH);
            const float v = __half2float(__ushort_as_half((unsigned short)(P >> 16)));
#pragma unroll
            for (int k = 0; k < 8; ++k)
                acc[k] = fmaf(v, bf2f((unsigned short)xv[k]), acc[k]);
        }
    }

#pragma unroll
    for (int k = 0; k < 8; ++k) {
        acc[k] += __shfl_xor(acc[k], 8, 64);
        acc[k] += __shfl_xor(acc[k], 16, 64);
        acc[k] += __shfl_xor(acc[k], 32, 64);
    }

    if (eslot == 0) {
        const int chb = cg * 8;
        if (LAST) {
            float* op = (float*)xout_ + (size_t)row * OUTCH + chb;
            const floatx4 b0 = *(const floatx4*)(bias + chb);
            const floatx4 b1 = *(const floatx4*)(bias + chb + 4);
            floatx4 o0, o1;
            o0[0] = acc[0] + b0[0]; o0[1] = acc[1] + b0[1];
            o0[2] = acc[2] + b0[2]; o0[3] = acc[3] + b0[3];
            o1[0] = acc[4] + b1[0]; o1[1] = acc[5] + b1[1];
            o1[2] = acc[6] + b1[2]; o1[3] = acc[7] + b1[3];
            __builtin_nontemporal_store(o0, (floatx4*)op);      // final out: true stream
            __builtin_nontemporal_store(o1, (floatx4*)(op + 4));
        } else {
            unsigned short* op = (unsigned short*)xout_ + (size_t)row * OUTCH + chb;
            short8 o;
#pragma unroll
            for (int k = 0; k < 8; ++k) o[k] = (short)f2bf(acc[k]);
            *(short8*)op = o;                 // x1 re-read by hop 2: cached
        }
    }
}

extern "C" void kernel_launch(void* const* d_in, const int* in_sizes, int n_in,
                              void* d_out, int out_size, void* d_ws, size_t ws_size,
                              hipStream_t stream) {
    const int*   adj   = (const int*)d_in[0];     // [2, E]
    const float* avals = (const float*)d_in[1];   // [E]
    const float* feat  = (const float*)d_in[2];   // [N, 512]
    const float* W     = (const float*)d_in[3];   // [512, 64]
    const float* bias  = (const float*)d_in[4];   // [64]
    float* out = (float*)d_out;

    const int E_ = in_sizes[1];
    const int* rows = adj;
    const int* cols = adj + E_;

    // workspace layout (16B-aligned segments), total ~30.1 MB
    unsigned short* x0  = (unsigned short*)d_ws;             // N*64 bf16 (6.4 MB)
    unsigned short* x1  = x0 + (size_t)NN * OUTCH;           // N*64 bf16 (6.4 MB)
    unsigned short* Wbf = x1 + (size_t)NN * OUTCH;           // 64*512 bf16 (64 KB)
    unsigned* ell = (unsigned*)(Wbf + (size_t)OUTCH * INCH); // N*48 u32 (9.6 MB)
    u64* gbuckets = (u64*)(ell + (size_t)NN * MAXD);         // 391*2400 u64 (7.5 MB)
    int* gtail = (int*)(gbuckets + (size_t)NB * BCAP);       // padded (25 KB)
    int* deg = gtail + NB * TSTR;                            // N int (200 KB)

    // ---- prep: zero padded tails + convert W to bf16 [n][k] ----
    prep_kernel<<<128, 256, 0, stream>>>(W, Wbf, gtail);

    // ---- dense projection (bf16 MFMA) ----
    gemm_kernel<<<GB, 256, 0, stream>>>(feat, Wbf, x0);

    // ---- LDS-chunked dense bucket append ----
    const size_t scatter_lds = (size_t)NB * LCAP * sizeof(u64) + NB * sizeof(int);
    scatter_chunked<<<SCB, 256, scatter_lds, stream>>>(rows, cols, avals,
                                                       gtail, gbuckets, E_);

    // ---- buckets -> ELL (coalesced) + deg ----
    bucketize<<<NB, 512, 0, stream>>>(gtail, gbuckets, ell, deg);

    // ---- two SpMM hops; bias fused into the last ----
    spmm_full<false><<<NN / 4, 256, 0, stream>>>(deg, ell, x0, x1, nullptr);
    spmm_full<true><<<NN / 4, 256, 0, stream>>>(deg, ell, x1, out, bias);
}

// Round 13
// 247.781 us; speedup vs baseline: 1.0758x; 1.0112x over previous
//
#include <hip/hip_runtime.h>
#include <hip/hip_bf16.h>
#include <hip/hip_fp16.h>

#define NN 50000
#define INCH 512
#define OUTCH 64
#define NTILES 3125       // 50000 / 16 (exact)
#define MAXD 48           // ELL slots per row; P(Poisson(16) > 48) ~ 1e-11 per row
#define GB 782            // gemm blocks: ceil(3125 tiles / 4 waves)
#define SCB 256           // scatter blocks (first in grid; 2 blocks/CU with gemm)
#define RPB 128           // rows per bucket
#define NB 391            // ceil(50000 / 128)
#define LCAP 20           // LDS records per (block,bucket) cell; lambda=8, spill P~4e-5
#define BCAP 2400         // records per global bucket: Poisson(2048) + 7.8 sigma
#define TSTR 16           // gtail counter stride (64 B)

typedef __attribute__((ext_vector_type(8))) short short8;
typedef __attribute__((ext_vector_type(4))) float floatx4;
typedef unsigned long long u64;

__device__ __forceinline__ unsigned packbf2(float a, float b) {
    __hip_bfloat162 h = __float22bfloat162_rn(make_float2(a, b));  // v_cvt_pk_bf16_f32 RNE
    unsigned r;
    __builtin_memcpy(&r, &h, 4);
    return r;
}
__device__ __forceinline__ unsigned short f2bf(float f) {
    unsigned u = __float_as_uint(f);
    return (unsigned short)((u + 0x7FFFu + ((u >> 16) & 1u)) >> 16);  // RNE
}
__device__ __forceinline__ float bf2f(unsigned short u) {
    return __uint_as_float(((unsigned)u) << 16);
}

// ------------- prep: zero padded bucket tails + convert W -> bf16 [n][k] ----------
__global__ __launch_bounds__(256) void prep_kernel(const float* __restrict__ W,
                                                   unsigned short* __restrict__ Wbf,
                                                   int* __restrict__ gtail) {
    const int i = blockIdx.x * 256 + threadIdx.x;
    if (i < (NB * TSTR + 3) / 4)
        *reinterpret_cast<uint4*>(gtail + i * 4) = uint4{0u, 0u, 0u, 0u};
    if (i < INCH * OUTCH) {
        const int k = i >> 6;          // W is [k][n], read coalesced
        const int n = i & 63;
        Wbf[n * INCH + k] = f2bf(W[i]);
    }
}

// -------- fused: [blocks 0..SCB) LDS-chunked scatter | [SCB..SCB+GB) gemm ----------
// The two phases are data-independent; heterogeneous blocks overlap them on the
// CUs (scatter first so its long-latency atomics start immediately, gemm
// backfills). Dynamic LDS = 64.1 KB -> 2 blocks/CU for both kinds.
// Scatter: per-bucket LDS cells flushed ONCE as contiguous runs via a single
// atomicAdd(tail, n) reservation (r12: cut scatter churn ~16 us); cell
// overflow takes the correctness-safe direct-global spill path.
__global__ __launch_bounds__(256, 2) void fused_gemm_scatter(
        const float* __restrict__ A, const unsigned short* __restrict__ Wbf,
        unsigned short* __restrict__ C,
        const int* __restrict__ rows, const int* __restrict__ cols,
        const float* __restrict__ vals, int* __restrict__ gtail,
        u64* __restrict__ gbuckets, int E_) {
    extern __shared__ char ldsraw[];
    const int t = threadIdx.x;

    if (blockIdx.x < SCB) {
        // ---------- LDS-chunked scatter ----------
        u64* lstage = (u64*)ldsraw;                      // [NB][LCAP]  62.6 KB
        int* lcnt = (int*)(lstage + (size_t)NB * LCAP);  // [NB]        1.6 KB

        for (int j = t; j < NB; j += 256) lcnt[j] = 0;
        __syncthreads();

        for (int e = blockIdx.x * 256 + t; e < E_; e += SCB * 256) {
            const int r = __builtin_nontemporal_load(rows + e);
            const int c = __builtin_nontemporal_load(cols + e);
            const float v = __builtin_nontemporal_load(vals + e);
            const unsigned short hv = __half_as_ushort(__float2half(v));
            const u64 rec = (u64)(unsigned)(r & 0xFFFF)
                          | ((u64)(unsigned)(c & 0xFFFF) << 16)
                          | ((u64)hv << 32);
            const int b = r >> 7;                        // bucket = row / 128
            const int pos = atomicAdd(&lcnt[b], 1);
            if (pos < LCAP) {
                lstage[(size_t)b * LCAP + pos] = rec;
            } else {                                     // rare spill: direct global
                const int gp = atomicAdd(&gtail[b * TSTR], 1);
                if (gp < BCAP) gbuckets[(size_t)b * BCAP + gp] = rec;
            }
        }
        __syncthreads();

        // one dense flush per non-empty cell
        for (int j = t; j < NB; j += 256) {
            int n = lcnt[j];
            n = n < LCAP ? n : LCAP;
            if (n > 0) {
                const int pos = atomicAdd(&gtail[j * TSTR], n);
                u64* dst = gbuckets + (size_t)j * BCAP;
                const u64* src = lstage + (size_t)j * LCAP;
                for (int k = 0; k < n; ++k)
                    if (pos + k < BCAP) dst[pos + k] = src[k];
            }
        }
        return;
    }

    // ---------- gemm part ----------
    unsigned short* ldsT = (unsigned short*)ldsraw;      // [4][16*64] 8 KB used
    const int lane = t & 63;
    const int wave = t >> 6;
    const int tile = (blockIdx.x - SCB) * 4 + wave;
    if (tile >= NTILES) return;
    const int rbase = tile * 16;
    const int frow = lane & 15;
    const int quad = lane >> 4;
    const float* Ap = A + (size_t)(rbase + frow) * INCH + quad * 8;
    const unsigned short* Bp = Wbf + frow * INCH + quad * 8;

    floatx4 acc[4] = {floatx4{0,0,0,0}, floatx4{0,0,0,0}, floatx4{0,0,0,0}, floatx4{0,0,0,0}};

#pragma unroll
    for (int c = 0; c < 16; ++c) {
        const float4 a0 = *(const float4*)(Ap + c * 32);
        const float4 a1 = *(const float4*)(Ap + c * 32 + 4);
        short8 bfr[4];
#pragma unroll
        for (int f = 0; f < 4; ++f)
            bfr[f] = *(const short8*)(Bp + (size_t)f * 16 * INCH + c * 32);
        uint4 au;
        au.x = packbf2(a0.x, a0.y);
        au.y = packbf2(a0.z, a0.w);
        au.z = packbf2(a1.x, a1.y);
        au.w = packbf2(a1.z, a1.w);
        const short8 af = *(const short8*)&au;
#pragma unroll
        for (int f = 0; f < 4; ++f)
            acc[f] = __builtin_amdgcn_mfma_f32_16x16x32_bf16(af, bfr[f], acc[f], 0, 0, 0);
    }

    // C/D layout: col = f*16 + frow, row = quad*4 + reg   [m89]
    unsigned short* myT = ldsT + wave * 1024;
#pragma unroll
    for (int f = 0; f < 4; ++f)
#pragma unroll
        for (int reg = 0; reg < 4; ++reg)
            myT[(quad * 4 + reg) * 64 + f * 16 + frow] = f2bf(acc[f][reg]);
    // wave-local: ds ordering handled by lgkmcnt, no barrier needed
    unsigned short* Cw = C + (size_t)rbase * OUTCH;
#pragma unroll
    for (int it = 0; it < 2; ++it) {
        const short8 v = *(const short8*)&myT[it * 512 + lane * 8];
        *(short8*)(Cw + it * 512 + lane * 8) = v;
    }
}

// ---------------- bucketize: block per 128-row bucket -> ELL slice + deg ----------
// ONE LDS atomic per record; ELL slice written fully coalesced (uint4).
__global__ __launch_bounds__(512) void bucketize(
        const int* __restrict__ gtail, const u64* __restrict__ gbuckets,
        unsigned* __restrict__ ell, int* __restrict__ deg) {
    __shared__ int cnt[RPB];
    __shared__ __align__(16) unsigned stage[RPB * MAXD];   // 24.5 KB
    const int t = threadIdx.x;
    const int b = blockIdx.x;                  // grid = NB

    if (t < RPB) cnt[t] = 0;
    for (int j = t; j < RPB * MAXD; j += 512) stage[j] = 0u;
    __syncthreads();

    int n = gtail[b * TSTR];
    n = n < BCAP ? n : BCAP;
    const u64* base = gbuckets + (size_t)b * BCAP;
    for (int i = t; i < n; i += 512) {
        const u64 rec = __builtin_nontemporal_load(base + i);
        const int rloc = (int)rec & 127;       // row & 127 (bucket = row>>7)
        const int slot = atomicAdd(&cnt[rloc], 1);
        if (slot < MAXD)
            stage[rloc * MAXD + slot] = (unsigned)(rec >> 16);  // col | hv<<16
    }
    __syncthreads();

    const int nrows = (NN - b * RPB) < RPB ? (NN - b * RPB) : RPB;  // last: 80
    uint4* dst = (uint4*)(ell + (size_t)b * RPB * MAXD);
    const uint4* src = (const uint4*)stage;
    for (int j = t; j < (nrows * MAXD) / 4; j += 512) dst[j] = src[j];
    if (t < nrows) {
        int d = cnt[t];
        deg[b * RPB + t] = d < MAXD ? d : MAXD;
    }
}

// ---------------- SpMM over ELL: wave per row, 8 edge-slots x 8 ch-lanes ----------
// ELL loads now CONDITIONAL on the wave-uniform round count (avg d=16 -> 2 of
// 6 rounds loaded): ELL stream 9.6 -> ~4 MB/hop. Gather structure frozen at
// the empirical ~2 TB/s random-line ceiling.
template <bool LAST>
__global__ __launch_bounds__(256) void spmm_full(const int* __restrict__ deg,
                                                 const unsigned* __restrict__ ell,
                                                 const unsigned short* __restrict__ xin,
                                                 void* __restrict__ xout_,
                                                 const float* __restrict__ bias) {
    const int t = threadIdx.x;
    const int lane = t & 63;
    const int eslot = lane >> 3;              // 0..7: edge slot group
    const int cg = lane & 7;                  // channel group: 8 ch (16B) each
    const int row = blockIdx.x * 4 + (t >> 6);   // grid = 12500, NN exact
    int d = deg[row];
    d = d < MAXD ? d : MAXD;
    const unsigned* eb = ell + (size_t)row * MAXD;

    unsigned p[6];
#pragma unroll
    for (int j = 0; j < 6; ++j)   // wave-uniform conditional load (round used?)
        p[j] = (8 * j < d) ? __builtin_nontemporal_load(eb + eslot + 8 * j) : 0u;
#pragma unroll
    for (int j = 0; j < 6; ++j)
        if (eslot + 8 * j >= d) p[j] = 0u;    // col 0, val 0 -> contributes 0

    const unsigned short* xh = xin + cg * 8;
    float acc[8] = {0.f, 0.f, 0.f, 0.f, 0.f, 0.f, 0.f, 0.f};

#pragma unroll
    for (int j = 0; j < 6; ++j) {
        if (d > 8 * j) {                      // wave-uniform round skip
            const unsigned P = p[j];
            const short8 xv = *(const short8*)(xh + (size_t)(P & 0xFFFFu) * OUTCH);
            const float v = __half2float(__ushort_as_half((unsigned short)(P >> 16)));
#pragma unroll
            for (int k = 0; k < 8; ++k)
                acc[k] = fmaf(v, bf2f((unsigned short)xv[k]), acc[k]);
        }
    }

#pragma unroll
    for (int k = 0; k < 8; ++k) {
        acc[k] += __shfl_xor(acc[k], 8, 64);
        acc[k] += __shfl_xor(acc[k], 16, 64);
        acc[k] += __shfl_xor(acc[k], 32, 64);
    }

    if (eslot == 0) {
        const int chb = cg * 8;
        if (LAST) {
            float* op = (float*)xout_ + (size_t)row * OUTCH + chb;
            const floatx4 b0 = *(const floatx4*)(bias + chb);
            const floatx4 b1 = *(const floatx4*)(bias + chb + 4);
            floatx4 o0, o1;
            o0[0] = acc[0] + b0[0]; o0[1] = acc[1] + b0[1];
            o0[2] = acc[2] + b0[2]; o0[3] = acc[3] + b0[3];
            o1[0] = acc[4] + b1[0]; o1[1] = acc[5] + b1[1];
            o1[2] = acc[6] + b1[2]; o1[3] = acc[7] + b1[3];
            __builtin_nontemporal_store(o0, (floatx4*)op);      // final out: true stream
            __builtin_nontemporal_store(o1, (floatx4*)(op + 4));
        } else {
            unsigned short* op = (unsigned short*)xout_ + (size_t)row * OUTCH + chb;
            short8 o;
#pragma unroll
            for (int k = 0; k < 8; ++k) o[k] = (short)f2bf(acc[k]);
            *(short8*)op = o;                 // x1 re-read by hop 2: cached
        }
    }
}

extern "C" void kernel_launch(void* const* d_in, const int* in_sizes, int n_in,
                              void* d_out, int out_size, void* d_ws, size_t ws_size,
                              hipStream_t stream) {
    const int*   adj   = (const int*)d_in[0];     // [2, E]
    const float* avals = (const float*)d_in[1];   // [E]
    const float* feat  = (const float*)d_in[2];   // [N, 512]
    const float* W     = (const float*)d_in[3];   // [512, 64]
    const float* bias  = (const float*)d_in[4];   // [64]
    float* out = (float*)d_out;

    const int E_ = in_sizes[1];
    const int* rows = adj;
    const int* cols = adj + E_;

    // workspace layout (16B-aligned segments), total ~30.1 MB
    unsigned short* x0  = (unsigned short*)d_ws;             // N*64 bf16 (6.4 MB)
    unsigned short* x1  = x0 + (size_t)NN * OUTCH;           // N*64 bf16 (6.4 MB)
    unsigned short* Wbf = x1 + (size_t)NN * OUTCH;           // 64*512 bf16 (64 KB)
    unsigned* ell = (unsigned*)(Wbf + (size_t)OUTCH * INCH); // N*48 u32 (9.6 MB)
    u64* gbuckets = (u64*)(ell + (size_t)NN * MAXD);         // 391*2400 u64 (7.5 MB)
    int* gtail = (int*)(gbuckets + (size_t)NB * BCAP);       // padded (25 KB)
    int* deg = gtail + NB * TSTR;                            // N int (200 KB)

    // ---- prep: zero padded tails + convert W to bf16 [n][k] ----
    prep_kernel<<<128, 256, 0, stream>>>(W, Wbf, gtail);

    // ---- fused: LDS-chunked scatter (blocks 0..255) + gemm (256..1037) ----
    const size_t fused_lds = (size_t)NB * LCAP * sizeof(u64) + NB * sizeof(int);
    fused_gemm_scatter<<<SCB + GB, 256, fused_lds, stream>>>(
        feat, Wbf, x0, rows, cols, avals, gtail, gbuckets, E_);

    // ---- buckets -> ELL (coalesced) + deg ----
    bucketize<<<NB, 512, 0, stream>>>(gtail, gbuckets, ell, deg);

    // ---- two SpMM hops; bias fused into the last ----
    spmm_full<false><<<NN / 4, 256, 0, stream>>>(deg, ell, x0, x1, nullptr);
    spmm_full<true><<<NN / 4, 256, 0, stream>>>(deg, ell, x1, out, bias);
}